// Round 14
// baseline (474.279 us; speedup 1.0000x reference)
//
#include <hip/hip_runtime.h>
#include <math.h>

#define N_NODES 50000
#define N_EDGES 800000
#define N_B     64

typedef __attribute__((ext_vector_type(8))) short v8s;
typedef __attribute__((ext_vector_type(4))) float v4f;
typedef __attribute__((ext_vector_type(2))) float v2f;

__device__ __forceinline__ float lrelu(float x){ return x > 0.f ? x : 0.2f*x; }
__device__ __forceinline__ unsigned short f2b(float f){   // fp32 -> bf16 RNE
  unsigned u = __float_as_uint(f);
  return (unsigned short)((u + 0x7fffu + ((u >> 16) & 1u)) >> 16);
}
__device__ __forceinline__ float blo(unsigned u){ return __uint_as_float(u << 16); }
__device__ __forceinline__ float bhi(unsigned u){ return __uint_as_float(u & 0xffff0000u); }

// ---------------- conv (weights->bf16^T, fused attn cols) + setup (cnt=0, bounds, out=0) ----------------
__global__ void k_convsetup(const float* __restrict__ Win, const float* __restrict__ Wl,
                            const float* __restrict__ a_src, const float* __restrict__ a_dst,
                            const float* __restrict__ Wg1, const int* __restrict__ batch,
                            unsigned short* __restrict__ WinT, unsigned short* __restrict__ WlT,
                            unsigned short* __restrict__ Wg1T, int* __restrict__ start,
                            int* __restrict__ cnt, float* __restrict__ out){
  if (blockIdx.x >= 384){                             // ---- setup part ----
    int i = (blockIdx.x - 384)*256 + threadIdx.x;
    if (i >= N_NODES) return;
    cnt[i] = 0;
    if (i < N_B*128) out[i] = 0.f;                    // k_pool accumulates into out
    int b = batch[i];
    int bp = (i == 0) ? -1 : batch[i-1];
    for (int j = bp+1; j <= b; j++) start[j] = i;
    if (i == N_NODES-1){
      for (int j = b+1; j <= N_B; j++) start[j] = N_NODES;
    }
    return;
  }
  int i = blockIdx.x*256 + threadIdx.x;
  if (i < 16384){
    int n = i >> 7, k = i & 127;
    WinT[n*128+k] = f2b(Win[k*128+n]);
    return;
  }
  i -= 16384;
  if (i < 65536){
    int l = i >> 14, n = (i >> 7) & 127, k = i & 127;
    WlT[l*144*128 + n*128 + k] = f2b(Wl[l*16384 + k*128 + n]);
    return;
  }
  i -= 65536;
  if (i < 4096){
    int l = i >> 10, k = (i >> 3) & 127, t = i & 7;
    int hh = t & 3, sd = t >> 2;
    const float* av = (sd ? a_dst : a_src) + l*128 + hh*32;
    const float* wr = Wl + l*16384 + k*128 + hh*32;
    float s = 0.f;
    #pragma unroll
    for (int c = 0; c < 32; c++) s = fmaf(wr[c], av[c], s);
    WlT[l*144*128 + (128 + sd*4 + hh)*128 + k] = f2b(s);
    return;
  }
  i -= 4096;
  if (i < 4096){
    int l = i >> 10, r = (i >> 7) & 7, k = i & 127;
    WlT[l*144*128 + (136+r)*128 + k] = 0;
    return;
  }
  i -= 4096;
  if (i < 8192){
    int n = i >> 7, k = i & 127;
    Wg1T[n*128+k] = f2b(Wg1[k*64+n]);
  }
}

// ---------------- degree histogram + per-edge rank: 8 edges/thread for atomic MLP ----------------
__global__ void k_hist(const int* __restrict__ ei, int* __restrict__ cnt, int* __restrict__ rank){
  int t = blockIdx.x*256 + threadIdx.x;
  if (t >= 100000) return;
  #pragma unroll
  for (int r = 0; r < 8; r++){
    int e = t + r*100000;
    int d = ei[N_EDGES + e];
    rank[e] = atomicAdd(&cnt[d], 1);
  }
}

// ---------------- scan1: per-block inclusive scan ----------------
__global__ void k_scan1(const int* __restrict__ cnt, int* __restrict__ incl, int* __restrict__ part){
  __shared__ int sh[256];
  int tid = threadIdx.x, i = blockIdx.x*256 + tid;
  int v = (i < N_NODES) ? cnt[i] : 0;
  sh[tid] = v; __syncthreads();
  for (int off = 1; off < 256; off <<= 1){
    int t = (tid >= off) ? sh[tid-off] : 0;
    __syncthreads();
    sh[tid] += t; __syncthreads();
  }
  if (i < N_NODES) incl[i] = sh[tid];
  if (tid == 255) part[blockIdx.x] = sh[255];
}
// ---------------- scan23: each block reduces part[0..blockIdx) then writes off ----------------
__global__ void k_scan23(const int* __restrict__ cnt, const int* __restrict__ incl,
                         const int* __restrict__ part, int* __restrict__ off){
  __shared__ int red[4];
  __shared__ int bsum;
  int tid = threadIdx.x, lane = tid & 63, wave = tid >> 6;
  int v = (tid < (int)blockIdx.x) ? part[tid] : 0;   // 196 blocks < 256 threads
  #pragma unroll
  for (int m = 1; m < 64; m <<= 1) v += __shfl_xor(v, m);
  if (lane == 0) red[wave] = v;
  __syncthreads();
  if (tid == 0) bsum = red[0]+red[1]+red[2]+red[3];
  __syncthreads();
  int i = blockIdx.x*256 + tid;
  if (i >= N_NODES) return;
  int e = incl[i] - cnt[i] + bsum;
  off[i] = e;
  if (i == N_NODES-1) off[N_NODES] = e + cnt[i];
}

// ---------------- CSR fill + edge MLP scalar (atomic-free, single 8B scatter) ----------------
// R12 lesson: two 4B scatters double write-allocate line traffic (84 vs 51 MB) — keep int2.
__global__ void k_fill(const float* __restrict__ ea, const float* __restrict__ We1,
                       const float* __restrict__ be1, const float* __restrict__ We2,
                       const float* __restrict__ be2, const int* __restrict__ ei,
                       const int* __restrict__ off, const int* __restrict__ rank,
                       int2* __restrict__ es){
  __shared__ float w0[16], w1[16], bb[16], w2s[16];
  __shared__ float b2s;
  int tid = threadIdx.x;
  if (tid < 16){
    w0[tid] = We1[tid]; w1[tid] = We1[16+tid]; bb[tid] = be1[tid];
    w2s[tid] = 0.25f*(We2[tid*4]+We2[tid*4+1]+We2[tid*4+2]+We2[tid*4+3]);
  }
  if (tid == 0) b2s = 0.25f*(be2[0]+be2[1]+be2[2]+be2[3]);
  __syncthreads();
  int t = blockIdx.x*256 + tid;
  if (t >= 100000) return;
  #pragma unroll
  for (int r = 0; r < 8; r++){
    int e = t + r*100000;
    float a0 = ea[2*e], a1 = ea[2*e+1];
    float s = b2s;
    #pragma unroll
    for (int j = 0; j < 16; j++){
      float v = fmaf(a0, w0[j], fmaf(a1, w1[j], bb[j]));
      v = v > 0.f ? v : 0.f;
      s = fmaf(v, w2s[j], s);
    }
    int d = ei[N_EDGES + e];
    int p = off[d] + rank[e];
    es[p] = make_int2(ei[e], __float_as_int(s));
  }
}

// ---------------- MFMA GEMM (A fp32 -> bf16 during LDS staging; B read DIRECT from
// global — B is block-shared (32-37 KB, L1/L2-hot), so staging it in LDS cost 39 KB
// LDS (56 KB total -> 2 blocks/CU). A-only LDS = 17 KB -> ~6-9 waves/SIMD. ----------------
template<int NT, int MODE>
__global__ __launch_bounds__(256) void k_mgemm(
    const float* __restrict__ A, const unsigned short* __restrict__ Bt,
    const float* __restrict__ bias,
    float* __restrict__ h,
    unsigned short* __restrict__ xpb, float* __restrict__ asn, float* __restrict__ adn,
    const float* __restrict__ Wg2, const float* __restrict__ bg2, float* __restrict__ gate)
{
  __shared__ __attribute__((aligned(16))) unsigned short As[4][16][136];
  int tid = threadIdx.x, wave = tid >> 6, lane = tid & 63;
  int l15 = lane & 15, quad = lane >> 4;
  int rbase = blockIdx.x * 64;
  for (int id = tid; id < 64*16; id += 256){
    int r = id >> 4, ch = id & 15;
    int gr = rbase + r;
    v8s v = {0,0,0,0,0,0,0,0};
    if (gr < N_NODES){
      const float* Af = A + (size_t)gr*128 + ch*8;
      float4 va = *(const float4*)Af;
      float4 vb = *(const float4*)(Af + 4);
      v[0]=(short)f2b(va.x); v[1]=(short)f2b(va.y); v[2]=(short)f2b(va.z); v[3]=(short)f2b(va.w);
      v[4]=(short)f2b(vb.x); v[5]=(short)f2b(vb.y); v[6]=(short)f2b(vb.z); v[7]=(short)f2b(vb.w);
    }
    *(v8s*)&As[r >> 4][r & 15][ch*8] = v;
  }
  __syncthreads();
  v4f acc[NT];
  #pragma unroll
  for (int t = 0; t < NT; t++) acc[t] = (v4f){0.f,0.f,0.f,0.f};
  const unsigned short* Bl = Bt + l15*128 + quad*8;   // per-lane B base (16B-aligned)
  #pragma unroll
  for (int kb = 0; kb < 4; kb++){
    v8s a = *(v8s*)&As[wave][l15][kb*32 + quad*8];
    #pragma unroll
    for (int ct = 0; ct < NT; ct++){
      v8s b = *(const v8s*)(Bl + ct*16*128 + kb*32);  // L1-hot: same B for all blocks
      acc[ct] = __builtin_amdgcn_mfma_f32_16x16x32_bf16(a, b, acc[ct], 0, 0, 0);
    }
  }
  int row0 = rbase + wave*16 + quad*4;
  if (MODE == 0){
    #pragma unroll
    for (int ct = 0; ct < 8; ct++){
      float bcol = bias[ct*16 + l15];
      #pragma unroll
      for (int r = 0; r < 4; r++){
        int gr = row0 + r;
        if (gr < N_NODES) h[(size_t)gr*128 + ct*16 + l15] = acc[ct][r] + bcol;
      }
    }
  } else if (MODE == 1){
    #pragma unroll
    for (int ct = 0; ct < 8; ct++){
      #pragma unroll
      for (int r = 0; r < 4; r++){
        int gr = row0 + r;
        if (gr < N_NODES) xpb[(size_t)gr*128 + ct*16 + l15] = f2b(acc[ct][r]);
      }
    }
    #pragma unroll
    for (int r = 0; r < 4; r++){
      int gr = row0 + r;
      if (gr < N_NODES){
        float v = acc[NT-1][r];
        if (l15 < 4) asn[gr*4 + l15] = v;
        else if (l15 < 8) adn[gr*4 + (l15-4)] = v;
      }
    }
  } else {
    float part[4] = {0.f,0.f,0.f,0.f};
    #pragma unroll
    for (int ct = 0; ct < NT; ct++){
      float b1 = bias[ct*16 + l15];
      float w2 = Wg2[ct*16 + l15];
      #pragma unroll
      for (int r = 0; r < 4; r++) part[r] = fmaf(tanhf(acc[ct][r] + b1), w2, part[r]);
    }
    #pragma unroll
    for (int m = 1; m < 16; m <<= 1){
      #pragma unroll
      for (int r = 0; r < 4; r++) part[r] += __shfl_xor(part[r], m);
    }
    if (l15 == 0){
      float b2 = bg2[0];
      #pragma unroll
      for (int r = 0; r < 4; r++){
        int gr = row0 + r;
        if (gr < N_NODES) gate[gr] = part[r] + b2;
      }
    }
  }
}

// ---------------- per-node GAT softmax + aggregate + bias + LN + crit + residual ----------------
// v11 (plateau-verified): e_self shift (no max reduce), in-register denom (no sum
// reduce), 12-deep branch-free gather pipeline; readlane index &63 + zero-padded
// LDS tail make padded iterations contribute exactly 0. Depth 16 REGRESSED
// (rounds avg deg 17 up to 32); 2-node interleave REGRESSED (occupancy cliff).
// TLP hides gather latency: VGPR 28, LDS 4.5KB.
template<bool CRIT>
__global__ __launch_bounds__(256) void k_aggr(
    const unsigned short* __restrict__ xpb, const float* __restrict__ asn,
    const float* __restrict__ adn, const int* __restrict__ off,
    const int2* __restrict__ es,
    const float* __restrict__ bl, const float* __restrict__ lng,
    const float* __restrict__ lnb, float* __restrict__ crit,
    float* __restrict__ h)
{
  __shared__ float lp[4][288];
  int wave = threadIdx.x >> 6, lane = threadIdx.x & 63;
  int n = blockIdx.x*4 + wave;
  if (n >= N_NODES) return;
  int base = off[n], deg = off[n+1] - base;
  float4 ad4 = *(const float4*)(adn + n*4);
  float4 asf = *(const float4*)(asn + n*4);
  float ex = lrelu(asf.x+ad4.x), ey = lrelu(asf.y+ad4.y);
  float ez = lrelu(asf.z+ad4.z), ew = lrelu(asf.w+ad4.w);
  const unsigned* xw = (const unsigned*)xpb;
  float* myp = &lp[wave][0];
  int hh = lane >> 4;
  float cr, dsum = 0.f;
  v2f acc;
  unsigned us = (xw + ((size_t)(unsigned)n << 6))[lane];
  acc.x = blo(us); acc.y = bhi(us);                   // self numerator == exp(0) == 1

  if (deg <= 64){
    int sreg = 0;
    float cw = 0.f;
    float p0 = 0.f, p1 = 0.f, p2 = 0.f, p3 = 0.f;
    if (lane < deg){
      int2 er = es[base + lane];
      sreg = er.x;
      float4 a = *(const float4*)(asn + sreg*4);
      p0 = __expf(lrelu(a.x+ad4.x) - ex);
      p1 = __expf(lrelu(a.y+ad4.y) - ey);
      p2 = __expf(lrelu(a.z+ad4.z) - ez);
      p3 = __expf(lrelu(a.w+ad4.w) - ew);
      if (CRIT) cw = __int_as_float(er.y);
    }
    if (CRIT){
      #pragma unroll
      for (int m = 1; m < 64; m <<= 1) cw += __shfl_xor(cw, m);
      if (lane == 0) crit[n] = cw;
      cr = cw;
    } else cr = crit[n];
    *(float4*)(&myp[4*lane]) = make_float4(p0,p1,p2,p3);
    if (lane < 8) *(float4*)(&myp[256 + 4*lane]) = make_float4(0.f,0.f,0.f,0.f);  // pad tail
    __threadfence_block();
    int degR = ((deg + 11) / 12) * 12;                 // <= 72; pad covers 256..287
    for (int c = 0; c < degR; c += 12){
      unsigned u[12];
      #pragma unroll
      for (int k = 0; k < 12; k++){
        int s0 = __builtin_amdgcn_readlane(sreg, (c + k) & 63);   // defined index
        u[k] = (xw + ((size_t)(unsigned)s0 << 6))[lane];          // SGPR base + lane*4
      }
      #pragma unroll
      for (int k = 0; k < 12; k++){
        float q = myp[4*(c+k) + hh];                   // q==0 beyond deg (incl. pad)
        dsum += q;                                     // full denom, no reduce
        v2f v = {blo(u[k]), bhi(u[k])};
        acc += q * v;
      }
    }
    __threadfence_block();
  } else {
    // ---- general path (rare): tile loop; crit pass only in layer 0 ----
    if (CRIT){
      float cw = 0.f;
      for (int j = lane; j < deg; j += 64) cw += __int_as_float(es[base + j].y);
      #pragma unroll
      for (int m = 1; m < 64; m <<= 1) cw += __shfl_xor(cw, m);
      if (lane == 0) crit[n] = cw;
      cr = cw;
    } else cr = crit[n];
    for (int j0 = 0; j0 < deg; j0 += 64){
      int clen = deg - j0; if (clen > 64) clen = 64;
      int sreg = 0;
      float p0 = 0.f, p1 = 0.f, p2 = 0.f, p3 = 0.f;
      if (lane < clen){
        sreg = es[base + j0 + lane].x;
        float4 a = *(const float4*)(asn + sreg*4);
        p0 = __expf(lrelu(a.x+ad4.x) - ex);
        p1 = __expf(lrelu(a.y+ad4.y) - ey);
        p2 = __expf(lrelu(a.z+ad4.z) - ez);
        p3 = __expf(lrelu(a.w+ad4.w) - ew);
      }
      *(float4*)(&myp[4*lane]) = make_float4(p0,p1,p2,p3);
      __threadfence_block();
      int clenR = (clen + 7) & ~7;                     // <= 64
      for (int c = 0; c < clenR; c += 8){
        unsigned u[8];
        #pragma unroll
        for (int k = 0; k < 8; k++){
          int s0 = __builtin_amdgcn_readlane(sreg, c + k);
          u[k] = (xw + ((size_t)(unsigned)s0 << 6))[lane];
        }
        #pragma unroll
        for (int k = 0; k < 8; k++){
          float q = myp[4*(c+k) + hh];
          dsum += q;
          v2f v = {blo(u[k]), bhi(u[k])};
          acc += q * v;
        }
      }
      __threadfence_block();
    }
  }
  float rden = 1.f / (dsum + 1.f + 1e-16f);            // +1 = self term
  int c0 = 2*lane;
  float2 blv = *(const float2*)(bl + c0);
  float o0 = acc.x*rden + blv.x;
  float o1 = acc.y*rden + blv.y;
  float su = o0 + o1, sq = o0*o0 + o1*o1;
  #pragma unroll
  for (int m = 1; m < 64; m <<= 1){ su += __shfl_xor(su, m); sq += __shfl_xor(sq, m); }
  float mu  = su * (1.f/128.f);
  float var = sq * (1.f/128.f) - mu*mu; var = var > 0.f ? var : 0.f;
  float inv = rsqrtf(var + 1e-5f);
  float2 rv  = *(const float2*)(h + (size_t)n*128 + c0);
  float2 gv  = *(const float2*)(lng + c0);
  float2 bv2 = *(const float2*)(lnb + c0);
  o0 = (o0-mu)*inv*gv.x + bv2.x + cr + rv.x;
  o1 = (o1-mu)*inv*gv.y + bv2.y + cr + rv.y;
  *(float2*)(&h[(size_t)n*128 + c0]) = make_float2(o0, o1);
}

// ---------------- pooling: 4 blocks per graph; A/B recomputed per block (no gate write),
// phase-C quarter partials accumulated into zero-initialized out via atomicAdd ----------------
__global__ __launch_bounds__(256) void k_pool(
    const float* __restrict__ h, const float* __restrict__ gate,
    const int* __restrict__ start, float* __restrict__ out)
{
  __shared__ float red[4];
  __shared__ float sbc;
  __shared__ float4 accs[8][32];
  int b = blockIdx.x >> 2, quarter = blockIdx.x & 3;
  int s0 = start[b], s1 = start[b+1];
  int tid = threadIdx.x, lane = tid & 63, wave = tid >> 6;
  float m = -3.0e38f;
  for (int i = s0 + tid; i < s1; i += 256) m = fmaxf(m, gate[i]);
  #pragma unroll
  for (int k = 1; k < 64; k <<= 1) m = fmaxf(m, __shfl_xor(m, k));
  if (lane == 0) red[wave] = m;
  __syncthreads();
  if (tid == 0) sbc = fmaxf(fmaxf(red[0],red[1]), fmaxf(red[2],red[3]));
  __syncthreads();
  float gm = sbc;
  __syncthreads();
  float s = 0.f;
  for (int i = s0 + tid; i < s1; i += 256) s += __expf(gate[i] - gm);
  #pragma unroll
  for (int k = 1; k < 64; k <<= 1) s += __shfl_xor(s, k);
  if (lane == 0) red[wave] = s;
  __syncthreads();
  if (tid == 0) sbc = red[0]+red[1]+red[2]+red[3];
  __syncthreads();
  float inv = 1.f / (sbc + 1e-16f);
  int c4 = (tid & 31) * 4;
  int g  = tid >> 5;
  float4 acc = make_float4(0.f,0.f,0.f,0.f);
  for (int i = s0 + quarter*8 + g; i < s1; i += 32){
    float p = __expf(gate[i] - gm);
    float4 hv = *(const float4*)(h + (size_t)i*128 + c4);
    acc.x = fmaf(p,hv.x,acc.x); acc.y = fmaf(p,hv.y,acc.y);
    acc.z = fmaf(p,hv.z,acc.z); acc.w = fmaf(p,hv.w,acc.w);
  }
  accs[g][tid & 31] = acc;
  __syncthreads();
  if (g == 0){
    float4 t = acc;
    #pragma unroll
    for (int k = 1; k < 8; k++){
      float4 o = accs[k][tid & 31];
      t.x += o.x; t.y += o.y; t.z += o.z; t.w += o.w;
    }
    atomicAdd(out + b*128 + c4 + 0, t.x*inv);
    atomicAdd(out + b*128 + c4 + 1, t.y*inv);
    atomicAdd(out + b*128 + c4 + 2, t.z*inv);
    atomicAdd(out + b*128 + c4 + 3, t.w*inv);
  }
}

extern "C" void kernel_launch(void* const* d_in, const int* in_sizes, int n_in,
                              void* d_out, int out_size, void* d_ws, size_t ws_size,
                              hipStream_t stream){
  (void)in_sizes; (void)n_in; (void)out_size; (void)ws_size;
  const float* x    = (const float*)d_in[0];
  const float* ea   = (const float*)d_in[1];
  const float* Win  = (const float*)d_in[2];
  const float* b_in = (const float*)d_in[3];
  const float* We1  = (const float*)d_in[4];
  const float* be1  = (const float*)d_in[5];
  const float* We2  = (const float*)d_in[6];
  const float* be2  = (const float*)d_in[7];
  const float* Wl   = (const float*)d_in[8];
  const float* a_src= (const float*)d_in[9];
  const float* a_dst= (const float*)d_in[10];
  const float* bl   = (const float*)d_in[11];
  const float* lng  = (const float*)d_in[12];
  const float* lnb  = (const float*)d_in[13];
  const float* Wg1  = (const float*)d_in[14];
  const float* bg1  = (const float*)d_in[15];
  const float* Wg2  = (const float*)d_in[16];
  const float* bg2  = (const float*)d_in[17];
  const int*   ei   = (const int*)d_in[18];
  const int*   batch= (const int*)d_in[19];
  float* out = (float*)d_out;

  char* w = (char*)d_ws;
  auto alloc = [&](size_t bytes){ char* p = w; w += (bytes + 255) & ~(size_t)255; return p; };
  float* h    = (float*)alloc((size_t)N_NODES*128*4);
  unsigned short* xpb = (unsigned short*)alloc((size_t)N_NODES*128*2);
  float* asn  = (float*)alloc((size_t)N_NODES*4*4);
  float* adn  = (float*)alloc((size_t)N_NODES*4*4);
  float* crit = (float*)alloc((size_t)N_NODES*4);
  int*   cnt  = (int*)alloc((size_t)N_NODES*4);
  int*   incl = (int*)alloc((size_t)N_NODES*4);
  int*   part = (int*)alloc(256*4);
  int*   off  = (int*)alloc((size_t)(N_NODES+1)*4);
  int*   rank = (int*)alloc((size_t)N_EDGES*4);
  int2*  es   = (int2*)alloc((size_t)N_EDGES*8);
  float* gate = (float*)alloc((size_t)N_NODES*4);
  int*   start= (int*)alloc((size_t)(N_B+1)*4);
  unsigned short* WinT = (unsigned short*)alloc((size_t)128*128*2);
  unsigned short* WlT  = (unsigned short*)alloc((size_t)4*144*128*2);
  unsigned short* Wg1T = (unsigned short*)alloc((size_t)64*128*2);

  int nb_n = (N_NODES + 255)/256;   // 196
  int nb_w = (N_NODES + 3)/4;       // 12500 (one wave per node)
  int nb_g = (N_NODES + 63)/64;     // 782
  int nb_cs = 384 + nb_n;           // conv blocks + setup blocks
  int nb_8e = (100000 + 255)/256;   // 391

  k_convsetup<<<nb_cs,256,0,stream>>>(Win, Wl, a_src, a_dst, Wg1, batch,
                                      WinT, WlT, Wg1T, start, cnt, out);
  k_hist<<<nb_8e,256,0,stream>>>(ei, cnt, rank);
  k_mgemm<8,0><<<nb_g,256,0,stream>>>(x, WinT, b_in, h,
                                      nullptr, nullptr, nullptr, nullptr, nullptr, nullptr);
  k_scan1<<<nb_n,256,0,stream>>>(cnt, incl, part);
  k_scan23<<<nb_n,256,0,stream>>>(cnt, incl, part, off);
  k_fill<<<nb_8e,256,0,stream>>>(ea, We1, be1, We2, be2, ei, off, rank, es);
  for (int l = 0; l < 4; l++){
    k_mgemm<9,1><<<nb_g,256,0,stream>>>(h, WlT + (size_t)l*144*128, nullptr, nullptr,
                                        xpb, asn, adn, nullptr, nullptr, nullptr);
    if (l == 0)
      k_aggr<true><<<nb_w,256,0,stream>>>(xpb, asn, adn, off, es,
                                          bl + l*128, lng + l*128, lnb + l*128, crit, h);
    else
      k_aggr<false><<<nb_w,256,0,stream>>>(xpb, asn, adn, off, es,
                                           bl + l*128, lng + l*128, lnb + l*128, crit, h);
  }
  k_mgemm<4,2><<<nb_g,256,0,stream>>>(h, Wg1T, bg1, nullptr,
                                      nullptr, nullptr, nullptr, Wg2, bg2, gate);
  k_pool<<<N_B*4,256,0,stream>>>(h, gate, start, out);
}

// Round 15
// 423.854 us; speedup vs baseline: 1.1190x; 1.1190x over previous
//
#include <hip/hip_runtime.h>
#include <math.h>

#define N_NODES 50000
#define N_EDGES 800000
#define N_B     64

typedef __attribute__((ext_vector_type(8))) short v8s;
typedef __attribute__((ext_vector_type(4))) float v4f;
typedef __attribute__((ext_vector_type(2))) float v2f;

__device__ __forceinline__ float lrelu(float x){ return x > 0.f ? x : 0.2f*x; }
__device__ __forceinline__ unsigned short f2b(float f){   // fp32 -> bf16 RNE
  unsigned u = __float_as_uint(f);
  return (unsigned short)((u + 0x7fffu + ((u >> 16) & 1u)) >> 16);
}
__device__ __forceinline__ float blo(unsigned u){ return __uint_as_float(u << 16); }
__device__ __forceinline__ float bhi(unsigned u){ return __uint_as_float(u & 0xffff0000u); }

// ---------------- conv (weights->bf16^T, fused attn cols) + setup (cnt=0, bounds, out=0) ----------------
__global__ void k_convsetup(const float* __restrict__ Win, const float* __restrict__ Wl,
                            const float* __restrict__ a_src, const float* __restrict__ a_dst,
                            const float* __restrict__ Wg1, const int* __restrict__ batch,
                            unsigned short* __restrict__ WinT, unsigned short* __restrict__ WlT,
                            unsigned short* __restrict__ Wg1T, int* __restrict__ start,
                            int* __restrict__ cnt, float* __restrict__ out){
  if (blockIdx.x >= 384){                             // ---- setup part ----
    int i = (blockIdx.x - 384)*256 + threadIdx.x;
    if (i >= N_NODES) return;
    cnt[i] = 0;
    if (i < N_B*128) out[i] = 0.f;                    // k_pool accumulates into out
    int b = batch[i];
    int bp = (i == 0) ? -1 : batch[i-1];
    for (int j = bp+1; j <= b; j++) start[j] = i;
    if (i == N_NODES-1){
      for (int j = b+1; j <= N_B; j++) start[j] = N_NODES;
    }
    return;
  }
  int i = blockIdx.x*256 + threadIdx.x;
  if (i < 16384){
    int n = i >> 7, k = i & 127;
    WinT[n*128+k] = f2b(Win[k*128+n]);
    return;
  }
  i -= 16384;
  if (i < 65536){
    int l = i >> 14, n = (i >> 7) & 127, k = i & 127;
    WlT[l*144*128 + n*128 + k] = f2b(Wl[l*16384 + k*128 + n]);
    return;
  }
  i -= 65536;
  if (i < 4096){
    int l = i >> 10, k = (i >> 3) & 127, t = i & 7;
    int hh = t & 3, sd = t >> 2;
    const float* av = (sd ? a_dst : a_src) + l*128 + hh*32;
    const float* wr = Wl + l*16384 + k*128 + hh*32;
    float s = 0.f;
    #pragma unroll
    for (int c = 0; c < 32; c++) s = fmaf(wr[c], av[c], s);
    WlT[l*144*128 + (128 + sd*4 + hh)*128 + k] = f2b(s);
    return;
  }
  i -= 4096;
  if (i < 4096){
    int l = i >> 10, r = (i >> 7) & 7, k = i & 127;
    WlT[l*144*128 + (136+r)*128 + k] = 0;
    return;
  }
  i -= 4096;
  if (i < 8192){
    int n = i >> 7, k = i & 127;
    Wg1T[n*128+k] = f2b(Wg1[k*64+n]);
  }
}

// ---------------- degree histogram + per-edge rank: 8 edges/thread for atomic MLP ----------------
__global__ void k_hist(const int* __restrict__ ei, int* __restrict__ cnt, int* __restrict__ rank){
  int t = blockIdx.x*256 + threadIdx.x;
  if (t >= 100000) return;
  #pragma unroll
  for (int r = 0; r < 8; r++){
    int e = t + r*100000;
    int d = ei[N_EDGES + e];
    rank[e] = atomicAdd(&cnt[d], 1);
  }
}

// ---------------- scan1: per-block inclusive scan ----------------
__global__ void k_scan1(const int* __restrict__ cnt, int* __restrict__ incl, int* __restrict__ part){
  __shared__ int sh[256];
  int tid = threadIdx.x, i = blockIdx.x*256 + tid;
  int v = (i < N_NODES) ? cnt[i] : 0;
  sh[tid] = v; __syncthreads();
  for (int off = 1; off < 256; off <<= 1){
    int t = (tid >= off) ? sh[tid-off] : 0;
    __syncthreads();
    sh[tid] += t; __syncthreads();
  }
  if (i < N_NODES) incl[i] = sh[tid];
  if (tid == 255) part[blockIdx.x] = sh[255];
}
// ---------------- scan23: each block reduces part[0..blockIdx) then writes off ----------------
__global__ void k_scan23(const int* __restrict__ cnt, const int* __restrict__ incl,
                         const int* __restrict__ part, int* __restrict__ off){
  __shared__ int red[4];
  __shared__ int bsum;
  int tid = threadIdx.x, lane = tid & 63, wave = tid >> 6;
  int v = (tid < (int)blockIdx.x) ? part[tid] : 0;   // 196 blocks < 256 threads
  #pragma unroll
  for (int m = 1; m < 64; m <<= 1) v += __shfl_xor(v, m);
  if (lane == 0) red[wave] = v;
  __syncthreads();
  if (tid == 0) bsum = red[0]+red[1]+red[2]+red[3];
  __syncthreads();
  int i = blockIdx.x*256 + tid;
  if (i >= N_NODES) return;
  int e = incl[i] - cnt[i] + bsum;
  off[i] = e;
  if (i == N_NODES-1) off[N_NODES] = e + cnt[i];
}

// ---------------- CSR fill + edge MLP scalar (atomic-free, single 8B scatter) ----------------
// R12 lesson: two 4B scatters double write-allocate line traffic (84 vs 51 MB) — keep int2.
__global__ void k_fill(const float* __restrict__ ea, const float* __restrict__ We1,
                       const float* __restrict__ be1, const float* __restrict__ We2,
                       const float* __restrict__ be2, const int* __restrict__ ei,
                       const int* __restrict__ off, const int* __restrict__ rank,
                       int2* __restrict__ es){
  __shared__ float w0[16], w1[16], bb[16], w2s[16];
  __shared__ float b2s;
  int tid = threadIdx.x;
  if (tid < 16){
    w0[tid] = We1[tid]; w1[tid] = We1[16+tid]; bb[tid] = be1[tid];
    w2s[tid] = 0.25f*(We2[tid*4]+We2[tid*4+1]+We2[tid*4+2]+We2[tid*4+3]);
  }
  if (tid == 0) b2s = 0.25f*(be2[0]+be2[1]+be2[2]+be2[3]);
  __syncthreads();
  int t = blockIdx.x*256 + tid;
  if (t >= 100000) return;
  #pragma unroll
  for (int r = 0; r < 8; r++){
    int e = t + r*100000;
    float a0 = ea[2*e], a1 = ea[2*e+1];
    float s = b2s;
    #pragma unroll
    for (int j = 0; j < 16; j++){
      float v = fmaf(a0, w0[j], fmaf(a1, w1[j], bb[j]));
      v = v > 0.f ? v : 0.f;
      s = fmaf(v, w2s[j], s);
    }
    int d = ei[N_EDGES + e];
    int p = off[d] + rank[e];
    es[p] = make_int2(ei[e], __float_as_int(s));
  }
}

// ---------------- MFMA GEMM (A fp32 -> bf16 during LDS staging; B staged in LDS —
// R14 lesson: B direct-from-global REGRESSED (9 LDS reads -> 36 VMEM loads/lane;
// the MFMA loop is memory-issue bound, not occupancy bound). Keep Bs. ----------------
template<int NT, int MODE>
__global__ __launch_bounds__(256) void k_mgemm(
    const float* __restrict__ A, const unsigned short* __restrict__ Bt,
    const float* __restrict__ bias,
    float* __restrict__ h,
    unsigned short* __restrict__ xpb, float* __restrict__ asn, float* __restrict__ adn,
    const float* __restrict__ Wg2, const float* __restrict__ bg2, float* __restrict__ gate)
{
  __shared__ __attribute__((aligned(16))) unsigned short Bs[NT*16][136];
  __shared__ __attribute__((aligned(16))) unsigned short As[4][16][136];
  int tid = threadIdx.x, wave = tid >> 6, lane = tid & 63;
  int l15 = lane & 15, quad = lane >> 4;
  int rbase = blockIdx.x * 64;
  for (int id = tid; id < NT*16*16; id += 256){
    int r = id >> 4, ch = id & 15;
    *(v8s*)&Bs[r][ch*8] = *(const v8s*)(Bt + r*128 + ch*8);
  }
  for (int id = tid; id < 64*16; id += 256){
    int r = id >> 4, ch = id & 15;
    int gr = rbase + r;
    v8s v = {0,0,0,0,0,0,0,0};
    if (gr < N_NODES){
      const float* Af = A + (size_t)gr*128 + ch*8;
      float4 va = *(const float4*)Af;
      float4 vb = *(const float4*)(Af + 4);
      v[0]=(short)f2b(va.x); v[1]=(short)f2b(va.y); v[2]=(short)f2b(va.z); v[3]=(short)f2b(va.w);
      v[4]=(short)f2b(vb.x); v[5]=(short)f2b(vb.y); v[6]=(short)f2b(vb.z); v[7]=(short)f2b(vb.w);
    }
    *(v8s*)&As[r >> 4][r & 15][ch*8] = v;
  }
  __syncthreads();
  v4f acc[NT];
  #pragma unroll
  for (int t = 0; t < NT; t++) acc[t] = (v4f){0.f,0.f,0.f,0.f};
  #pragma unroll
  for (int kb = 0; kb < 4; kb++){
    v8s a = *(v8s*)&As[wave][l15][kb*32 + quad*8];
    #pragma unroll
    for (int ct = 0; ct < NT; ct++){
      v8s b = *(v8s*)&Bs[ct*16 + l15][kb*32 + quad*8];
      acc[ct] = __builtin_amdgcn_mfma_f32_16x16x32_bf16(a, b, acc[ct], 0, 0, 0);
    }
  }
  int row0 = rbase + wave*16 + quad*4;
  if (MODE == 0){
    #pragma unroll
    for (int ct = 0; ct < 8; ct++){
      float bcol = bias[ct*16 + l15];
      #pragma unroll
      for (int r = 0; r < 4; r++){
        int gr = row0 + r;
        if (gr < N_NODES) h[(size_t)gr*128 + ct*16 + l15] = acc[ct][r] + bcol;
      }
    }
  } else if (MODE == 1){
    #pragma unroll
    for (int ct = 0; ct < 8; ct++){
      #pragma unroll
      for (int r = 0; r < 4; r++){
        int gr = row0 + r;
        if (gr < N_NODES) xpb[(size_t)gr*128 + ct*16 + l15] = f2b(acc[ct][r]);
      }
    }
    #pragma unroll
    for (int r = 0; r < 4; r++){
      int gr = row0 + r;
      if (gr < N_NODES){
        float v = acc[NT-1][r];
        if (l15 < 4) asn[gr*4 + l15] = v;
        else if (l15 < 8) adn[gr*4 + (l15-4)] = v;
      }
    }
  } else {
    float part[4] = {0.f,0.f,0.f,0.f};
    #pragma unroll
    for (int ct = 0; ct < NT; ct++){
      float b1 = bias[ct*16 + l15];
      float w2 = Wg2[ct*16 + l15];
      #pragma unroll
      for (int r = 0; r < 4; r++) part[r] = fmaf(tanhf(acc[ct][r] + b1), w2, part[r]);
    }
    #pragma unroll
    for (int m = 1; m < 16; m <<= 1){
      #pragma unroll
      for (int r = 0; r < 4; r++) part[r] += __shfl_xor(part[r], m);
    }
    if (l15 == 0){
      float b2 = bg2[0];
      #pragma unroll
      for (int r = 0; r < 4; r++){
        int gr = row0 + r;
        if (gr < N_NODES) gate[gr] = part[r] + b2;
      }
    }
  }
}

// ---------------- per-node GAT softmax + aggregate + bias + LN + crit + residual ----------------
// v11 (plateau-verified): e_self shift (no max reduce), in-register denom (no sum
// reduce), 12-deep branch-free gather pipeline; readlane index &63 + zero-padded
// LDS tail make padded iterations contribute exactly 0. Depth 16 REGRESSED
// (rounds avg deg 17 up to 32); 2-node interleave REGRESSED (occupancy cliff).
// TLP hides gather latency: VGPR 28, LDS 4.5KB.
template<bool CRIT>
__global__ __launch_bounds__(256) void k_aggr(
    const unsigned short* __restrict__ xpb, const float* __restrict__ asn,
    const float* __restrict__ adn, const int* __restrict__ off,
    const int2* __restrict__ es,
    const float* __restrict__ bl, const float* __restrict__ lng,
    const float* __restrict__ lnb, float* __restrict__ crit,
    float* __restrict__ h)
{
  __shared__ float lp[4][288];
  int wave = threadIdx.x >> 6, lane = threadIdx.x & 63;
  int n = blockIdx.x*4 + wave;
  if (n >= N_NODES) return;
  int base = off[n], deg = off[n+1] - base;
  float4 ad4 = *(const float4*)(adn + n*4);
  float4 asf = *(const float4*)(asn + n*4);
  float ex = lrelu(asf.x+ad4.x), ey = lrelu(asf.y+ad4.y);
  float ez = lrelu(asf.z+ad4.z), ew = lrelu(asf.w+ad4.w);
  const unsigned* xw = (const unsigned*)xpb;
  float* myp = &lp[wave][0];
  int hh = lane >> 4;
  float cr, dsum = 0.f;
  v2f acc;
  unsigned us = (xw + ((size_t)(unsigned)n << 6))[lane];
  acc.x = blo(us); acc.y = bhi(us);                   // self numerator == exp(0) == 1

  if (deg <= 64){
    int sreg = 0;
    float cw = 0.f;
    float p0 = 0.f, p1 = 0.f, p2 = 0.f, p3 = 0.f;
    if (lane < deg){
      int2 er = es[base + lane];
      sreg = er.x;
      float4 a = *(const float4*)(asn + sreg*4);
      p0 = __expf(lrelu(a.x+ad4.x) - ex);
      p1 = __expf(lrelu(a.y+ad4.y) - ey);
      p2 = __expf(lrelu(a.z+ad4.z) - ez);
      p3 = __expf(lrelu(a.w+ad4.w) - ew);
      if (CRIT) cw = __int_as_float(er.y);
    }
    if (CRIT){
      #pragma unroll
      for (int m = 1; m < 64; m <<= 1) cw += __shfl_xor(cw, m);
      if (lane == 0) crit[n] = cw;
      cr = cw;
    } else cr = crit[n];
    *(float4*)(&myp[4*lane]) = make_float4(p0,p1,p2,p3);
    if (lane < 8) *(float4*)(&myp[256 + 4*lane]) = make_float4(0.f,0.f,0.f,0.f);  // pad tail
    __threadfence_block();
    int degR = ((deg + 11) / 12) * 12;                 // <= 72; pad covers 256..287
    for (int c = 0; c < degR; c += 12){
      unsigned u[12];
      #pragma unroll
      for (int k = 0; k < 12; k++){
        int s0 = __builtin_amdgcn_readlane(sreg, (c + k) & 63);   // defined index
        u[k] = (xw + ((size_t)(unsigned)s0 << 6))[lane];          // SGPR base + lane*4
      }
      #pragma unroll
      for (int k = 0; k < 12; k++){
        float q = myp[4*(c+k) + hh];                   // q==0 beyond deg (incl. pad)
        dsum += q;                                     // full denom, no reduce
        v2f v = {blo(u[k]), bhi(u[k])};
        acc += q * v;
      }
    }
    __threadfence_block();
  } else {
    // ---- general path (rare): tile loop; crit pass only in layer 0 ----
    if (CRIT){
      float cw = 0.f;
      for (int j = lane; j < deg; j += 64) cw += __int_as_float(es[base + j].y);
      #pragma unroll
      for (int m = 1; m < 64; m <<= 1) cw += __shfl_xor(cw, m);
      if (lane == 0) crit[n] = cw;
      cr = cw;
    } else cr = crit[n];
    for (int j0 = 0; j0 < deg; j0 += 64){
      int clen = deg - j0; if (clen > 64) clen = 64;
      int sreg = 0;
      float p0 = 0.f, p1 = 0.f, p2 = 0.f, p3 = 0.f;
      if (lane < clen){
        sreg = es[base + j0 + lane].x;
        float4 a = *(const float4*)(asn + sreg*4);
        p0 = __expf(lrelu(a.x+ad4.x) - ex);
        p1 = __expf(lrelu(a.y+ad4.y) - ey);
        p2 = __expf(lrelu(a.z+ad4.z) - ez);
        p3 = __expf(lrelu(a.w+ad4.w) - ew);
      }
      *(float4*)(&myp[4*lane]) = make_float4(p0,p1,p2,p3);
      __threadfence_block();
      int clenR = (clen + 7) & ~7;                     // <= 64
      for (int c = 0; c < clenR; c += 8){
        unsigned u[8];
        #pragma unroll
        for (int k = 0; k < 8; k++){
          int s0 = __builtin_amdgcn_readlane(sreg, c + k);
          u[k] = (xw + ((size_t)(unsigned)s0 << 6))[lane];
        }
        #pragma unroll
        for (int k = 0; k < 8; k++){
          float q = myp[4*(c+k) + hh];
          dsum += q;
          v2f v = {blo(u[k]), bhi(u[k])};
          acc += q * v;
        }
      }
      __threadfence_block();
    }
  }
  float rden = 1.f / (dsum + 1.f + 1e-16f);            // +1 = self term
  int c0 = 2*lane;
  float2 blv = *(const float2*)(bl + c0);
  float o0 = acc.x*rden + blv.x;
  float o1 = acc.y*rden + blv.y;
  float su = o0 + o1, sq = o0*o0 + o1*o1;
  #pragma unroll
  for (int m = 1; m < 64; m <<= 1){ su += __shfl_xor(su, m); sq += __shfl_xor(sq, m); }
  float mu  = su * (1.f/128.f);
  float var = sq * (1.f/128.f) - mu*mu; var = var > 0.f ? var : 0.f;
  float inv = rsqrtf(var + 1e-5f);
  float2 rv  = *(const float2*)(h + (size_t)n*128 + c0);
  float2 gv  = *(const float2*)(lng + c0);
  float2 bv2 = *(const float2*)(lnb + c0);
  o0 = (o0-mu)*inv*gv.x + bv2.x + cr + rv.x;
  o1 = (o1-mu)*inv*gv.y + bv2.y + cr + rv.y;
  *(float2*)(&h[(size_t)n*128 + c0]) = make_float2(o0, o1);
}

// ---------------- pooling: 4 blocks per graph; A/B recomputed per block (no gate write),
// phase-C quarter partials accumulated into zero-initialized out via atomicAdd ----------------
__global__ __launch_bounds__(256) void k_pool(
    const float* __restrict__ h, const float* __restrict__ gate,
    const int* __restrict__ start, float* __restrict__ out)
{
  __shared__ float red[4];
  __shared__ float sbc;
  __shared__ float4 accs[8][32];
  int b = blockIdx.x >> 2, quarter = blockIdx.x & 3;
  int s0 = start[b], s1 = start[b+1];
  int tid = threadIdx.x, lane = tid & 63, wave = tid >> 6;
  float m = -3.0e38f;
  for (int i = s0 + tid; i < s1; i += 256) m = fmaxf(m, gate[i]);
  #pragma unroll
  for (int k = 1; k < 64; k <<= 1) m = fmaxf(m, __shfl_xor(m, k));
  if (lane == 0) red[wave] = m;
  __syncthreads();
  if (tid == 0) sbc = fmaxf(fmaxf(red[0],red[1]), fmaxf(red[2],red[3]));
  __syncthreads();
  float gm = sbc;
  __syncthreads();
  float s = 0.f;
  for (int i = s0 + tid; i < s1; i += 256) s += __expf(gate[i] - gm);
  #pragma unroll
  for (int k = 1; k < 64; k <<= 1) s += __shfl_xor(s, k);
  if (lane == 0) red[wave] = s;
  __syncthreads();
  if (tid == 0) sbc = red[0]+red[1]+red[2]+red[3];
  __syncthreads();
  float inv = 1.f / (sbc + 1e-16f);
  int c4 = (tid & 31) * 4;
  int g  = tid >> 5;
  float4 acc = make_float4(0.f,0.f,0.f,0.f);
  for (int i = s0 + quarter*8 + g; i < s1; i += 32){
    float p = __expf(gate[i] - gm);
    float4 hv = *(const float4*)(h + (size_t)i*128 + c4);
    acc.x = fmaf(p,hv.x,acc.x); acc.y = fmaf(p,hv.y,acc.y);
    acc.z = fmaf(p,hv.z,acc.z); acc.w = fmaf(p,hv.w,acc.w);
  }
  accs[g][tid & 31] = acc;
  __syncthreads();
  if (g == 0){
    float4 t = acc;
    #pragma unroll
    for (int k = 1; k < 8; k++){
      float4 o = accs[k][tid & 31];
      t.x += o.x; t.y += o.y; t.z += o.z; t.w += o.w;
    }
    atomicAdd(out + b*128 + c4 + 0, t.x*inv);
    atomicAdd(out + b*128 + c4 + 1, t.y*inv);
    atomicAdd(out + b*128 + c4 + 2, t.z*inv);
    atomicAdd(out + b*128 + c4 + 3, t.w*inv);
  }
}

extern "C" void kernel_launch(void* const* d_in, const int* in_sizes, int n_in,
                              void* d_out, int out_size, void* d_ws, size_t ws_size,
                              hipStream_t stream){
  (void)in_sizes; (void)n_in; (void)out_size; (void)ws_size;
  const float* x    = (const float*)d_in[0];
  const float* ea   = (const float*)d_in[1];
  const float* Win  = (const float*)d_in[2];
  const float* b_in = (const float*)d_in[3];
  const float* We1  = (const float*)d_in[4];
  const float* be1  = (const float*)d_in[5];
  const float* We2  = (const float*)d_in[6];
  const float* be2  = (const float*)d_in[7];
  const float* Wl   = (const float*)d_in[8];
  const float* a_src= (const float*)d_in[9];
  const float* a_dst= (const float*)d_in[10];
  const float* bl   = (const float*)d_in[11];
  const float* lng  = (const float*)d_in[12];
  const float* lnb  = (const float*)d_in[13];
  const float* Wg1  = (const float*)d_in[14];
  const float* bg1  = (const float*)d_in[15];
  const float* Wg2  = (const float*)d_in[16];
  const float* bg2  = (const float*)d_in[17];
  const int*   ei   = (const int*)d_in[18];
  const int*   batch= (const int*)d_in[19];
  float* out = (float*)d_out;

  char* w = (char*)d_ws;
  auto alloc = [&](size_t bytes){ char* p = w; w += (bytes + 255) & ~(size_t)255; return p; };
  float* h    = (float*)alloc((size_t)N_NODES*128*4);
  unsigned short* xpb = (unsigned short*)alloc((size_t)N_NODES*128*2);
  float* asn  = (float*)alloc((size_t)N_NODES*4*4);
  float* adn  = (float*)alloc((size_t)N_NODES*4*4);
  float* crit = (float*)alloc((size_t)N_NODES*4);
  int*   cnt  = (int*)alloc((size_t)N_NODES*4);
  int*   incl = (int*)alloc((size_t)N_NODES*4);
  int*   part = (int*)alloc(256*4);
  int*   off  = (int*)alloc((size_t)(N_NODES+1)*4);
  int*   rank = (int*)alloc((size_t)N_EDGES*4);
  int2*  es   = (int2*)alloc((size_t)N_EDGES*8);
  float* gate = (float*)alloc((size_t)N_NODES*4);
  int*   start= (int*)alloc((size_t)(N_B+1)*4);
  unsigned short* WinT = (unsigned short*)alloc((size_t)128*128*2);
  unsigned short* WlT  = (unsigned short*)alloc((size_t)4*144*128*2);
  unsigned short* Wg1T = (unsigned short*)alloc((size_t)64*128*2);

  int nb_n = (N_NODES + 255)/256;   // 196
  int nb_w = (N_NODES + 3)/4;       // 12500 (one wave per node)
  int nb_g = (N_NODES + 63)/64;     // 782
  int nb_cs = 384 + nb_n;           // conv blocks + setup blocks
  int nb_8e = (100000 + 255)/256;   // 391

  k_convsetup<<<nb_cs,256,0,stream>>>(Win, Wl, a_src, a_dst, Wg1, batch,
                                      WinT, WlT, Wg1T, start, cnt, out);
  k_hist<<<nb_8e,256,0,stream>>>(ei, cnt, rank);
  k_mgemm<8,0><<<nb_g,256,0,stream>>>(x, WinT, b_in, h,
                                      nullptr, nullptr, nullptr, nullptr, nullptr, nullptr);
  k_scan1<<<nb_n,256,0,stream>>>(cnt, incl, part);
  k_scan23<<<nb_n,256,0,stream>>>(cnt, incl, part, off);
  k_fill<<<nb_8e,256,0,stream>>>(ea, We1, be1, We2, be2, ei, off, rank, es);
  for (int l = 0; l < 4; l++){
    k_mgemm<9,1><<<nb_g,256,0,stream>>>(h, WlT + (size_t)l*144*128, nullptr, nullptr,
                                        xpb, asn, adn, nullptr, nullptr, nullptr);
    if (l == 0)
      k_aggr<true><<<nb_w,256,0,stream>>>(xpb, asn, adn, off, es,
                                          bl + l*128, lng + l*128, lnb + l*128, crit, h);
    else
      k_aggr<false><<<nb_w,256,0,stream>>>(xpb, asn, adn, off, es,
                                           bl + l*128, lng + l*128, lnb + l*128, crit, h);
  }
  k_mgemm<4,2><<<nb_g,256,0,stream>>>(h, Wg1T, bg1, nullptr,
                                      nullptr, nullptr, nullptr, Wg2, bg2, gate);
  k_pool<<<N_B*4,256,0,stream>>>(h, gate, start, out);
}